// Round 1
// baseline (111.878 us; speedup 1.0000x reference)
//
#include <hip/hip_runtime.h>
#include <hip/hip_bf16.h>

#define MARGIN 0.1f
#define N 8192
#define D 128

typedef __attribute__((ext_vector_type(8))) short bf16x8;
typedef __attribute__((ext_vector_type(4))) float f32x4;

static __device__ __forceinline__ unsigned short f2bf(float f) {
    union { float f; unsigned int u; } x;
    x.f = f;
    // round-to-nearest-even
    unsigned int r = ((x.u >> 16) & 1u) + 0x7FFFu;
    return (unsigned short)((x.u + r) >> 16);
}

// Kernel 1: convert E (fp32) -> bf16 in workspace; zero rowsum accumulator.
__global__ void prep_kernel(const float* __restrict__ E,
                            unsigned short* __restrict__ Eb,
                            float* __restrict__ rowsum) {
    int idx = blockIdx.x * 256 + threadIdx.x;   // 262144 threads, 4 elems each
    float4 v = ((const float4*)E)[idx];
    ushort4 o;
    o.x = f2bf(v.x); o.y = f2bf(v.y); o.z = f2bf(v.z); o.w = f2bf(v.w);
    ((ushort4*)Eb)[idx] = o;
    if (idx < N) rowsum[idx] = 0.0f;
}

// Kernel 2: fused sim = E*E^T -> exp(+/-(sim-margin)) -> row sums.
// Wave layout: 2048 waves total. wave = strip(128) x chunk(16).
// Each wave: rows [strip*64, strip*64+64), cols [chunk*512, chunk*512+512).
// MFMA 16x16x32 bf16; A frags (4 row-groups x 4 k-steps) held in registers.
__global__ __launch_bounds__(256) void fused_kernel(
        const unsigned short* __restrict__ Eb,
        const int* __restrict__ labels,
        float* __restrict__ rowsum) {
    const int wave  = (blockIdx.x << 2) + (threadIdx.x >> 6); // 0..2047
    const int strip = wave >> 4;   // 0..127
    const int chunk = wave & 15;   // 0..15
    const int m0 = strip * 64;
    const int n_begin = chunk * 512;
    const int lane = threadIdx.x & 63;
    const int q = lane >> 4;       // 0..3
    const int l = lane & 15;       // 0..15

    // Load A fragments: a[g][kk] = E[m0+g*16+l][kk*32 + q*8 .. +7]
    bf16x8 a[4][4];
#pragma unroll
    for (int g = 0; g < 4; ++g) {
        const bf16x8* p = (const bf16x8*)(Eb + (size_t)(m0 + g * 16 + l) * D + q * 8);
#pragma unroll
        for (int kk = 0; kk < 4; ++kk) a[g][kk] = p[kk * 4]; // +kk*32 elems
    }

    // Row labels for the 16 (g,r) output rows this lane owns.
    int lrow[16];
#pragma unroll
    for (int g = 0; g < 4; ++g)
#pragma unroll
        for (int r = 0; r < 4; ++r)
            lrow[g * 4 + r] = labels[m0 + g * 16 + q * 4 + r];

    float sum[16];
#pragma unroll
    for (int i = 0; i < 16; ++i) sum[i] = 0.0f;

    for (int t = 0; t < 32; ++t) {
        const int n0 = n_begin + t * 16;
        const int col = n0 + l;
        const int lcol = labels[col];
        const bf16x8* bp = (const bf16x8*)(Eb + (size_t)col * D + q * 8);
        bf16x8 b[4];
#pragma unroll
        for (int kk = 0; kk < 4; ++kk) b[kk] = bp[kk * 4];

        f32x4 acc[4];
#pragma unroll
        for (int g = 0; g < 4; ++g) {
            acc[g] = (f32x4){0.f, 0.f, 0.f, 0.f};
#pragma unroll
            for (int kk = 0; kk < 4; ++kk)
                acc[g] = __builtin_amdgcn_mfma_f32_16x16x32_bf16(a[g][kk], b[kk], acc[g], 0, 0, 0);
        }

#pragma unroll
        for (int g = 0; g < 4; ++g) {
#pragma unroll
            for (int r = 0; r < 4; ++r) {
                float s = acc[g][r];
                bool eq = (lrow[g * 4 + r] == lcol);
                float arg = eq ? (MARGIN - s) : (s - MARGIN);
                sum[g * 4 + r] += __expf(arg);
            }
        }
    }

    // Reduce across the 16 column-lanes (xor masks 1,2,4,8 keep q fixed).
#pragma unroll
    for (int i = 0; i < 16; ++i) {
        float v = sum[i];
        v += __shfl_xor(v, 1);
        v += __shfl_xor(v, 2);
        v += __shfl_xor(v, 4);
        v += __shfl_xor(v, 8);
        sum[i] = v;
    }
    if (l == 0) {
#pragma unroll
        for (int g = 0; g < 4; ++g)
#pragma unroll
            for (int r = 0; r < 4; ++r)
                atomicAdd(&rowsum[m0 + g * 16 + q * 4 + r], sum[g * 4 + r]);
    }
}

// Kernel 3: loss = mean_i log(rowsum[i])
__global__ void finalize_kernel(const float* __restrict__ rowsum, float* __restrict__ out) {
    __shared__ float red[4];
    int tid = threadIdx.x;
    float s = 0.0f;
    for (int i = tid; i < N; i += 256) s += logf(rowsum[i]);
#pragma unroll
    for (int off = 32; off >= 1; off >>= 1) s += __shfl_down(s, off);
    if ((tid & 63) == 0) red[tid >> 6] = s;
    __syncthreads();
    if (tid == 0) out[0] = (red[0] + red[1] + red[2] + red[3]) * (1.0f / (float)N);
}

extern "C" void kernel_launch(void* const* d_in, const int* in_sizes, int n_in,
                              void* d_out, int out_size, void* d_ws, size_t ws_size,
                              hipStream_t stream) {
    const float* E = (const float*)d_in[0];
    const int* labels = (const int*)d_in[1];
    float* out = (float*)d_out;

    unsigned short* Eb = (unsigned short*)d_ws;                       // 8192*128*2 = 2 MiB
    float* rowsum = (float*)((char*)d_ws + (size_t)N * D * sizeof(unsigned short)); // 32 KiB

    prep_kernel<<<1024, 256, 0, stream>>>(E, Eb, rowsum);
    fused_kernel<<<512, 256, 0, stream>>>(Eb, labels, rowsum);
    finalize_kernel<<<1, 256, 0, stream>>>(rowsum, out);
}